// Round 1
// 1351.561 us; speedup vs baseline: 1.0796x; 1.0796x over previous
//
#include <hip/hip_runtime.h>

#define N_CTX 4096
#define DHEAD 64
#define NBH   16
#define NT    (N_CTX / 64)
#define LDT   72   // f16 row stride for 64-wide LDS tiles (64 + 8 pad)

typedef _Float16 half8 __attribute__((ext_vector_type(8)));
typedef _Float16 half4 __attribute__((ext_vector_type(4)));
typedef float    f32x4 __attribute__((ext_vector_type(4)));

__global__ __launch_bounds__(256, 4)
void attn_fused(const float* __restrict__ Q, const float* __restrict__ K,
                const float* __restrict__ V, float* __restrict__ out)
{
    const int tid  = threadIdx.x;
    const int wave = tid >> 6;
    const int lane = tid & 63;
    const int l15  = lane & 15;
    const int quad = lane >> 4;

    // XCD-aware remap (dispatch d -> XCD d%8 heuristic): each XCD owns 2 bh,
    // so its K+V working set (4 MB) exactly fits its private L2.
    const int dd     = blockIdx.y * 64 + blockIdx.x;
    const int c      = dd >> 3;
    const int bh     = 2 * (dd & 7) + (c >> 6);
    const int rowblk = c & 63;

    __shared__ __attribute__((aligned(16))) _Float16 s_k[64 * LDT];      // [key][d]
    __shared__ __attribute__((aligned(16))) _Float16 s_v[64 * LDT];      // V^T: [d][key]
    __shared__ __attribute__((aligned(16))) _Float16 s_p[4][16 * LDT];   // per-wave P[q][key]

    const size_t base = (size_t)bh * N_CTX * DHEAD;
    const int gr0 = rowblk * 64 + wave * 16;

    // Q as MFMA B-operand: lane holds Q[gr0+l15][8*quad+i] (i<8; +32 in aq[1]),
    // scale 1/8 folded (exact in f16)
    half8 aq[2];
    {
        const float* qp = Q + base + (size_t)(gr0 + l15) * DHEAD;
        #pragma unroll
        for (int h = 0; h < 2; ++h) {
            const float4 f0 = *(const float4*)(qp + 32*h + 8*quad);
            const float4 f1 = *(const float4*)(qp + 32*h + 8*quad + 4);
            half8 a;
            a[0]=(_Float16)(f0.x*0.125f); a[1]=(_Float16)(f0.y*0.125f);
            a[2]=(_Float16)(f0.z*0.125f); a[3]=(_Float16)(f0.w*0.125f);
            a[4]=(_Float16)(f1.x*0.125f); a[5]=(_Float16)(f1.y*0.125f);
            a[6]=(_Float16)(f1.z*0.125f); a[7]=(_Float16)(f1.w*0.125f);
            aq[h] = a;
        }
    }

    // staging decomposition: thread -> (row = tid>>2, 16-wide col group = tid&3)
    const int st_row = tid >> 2;          // K: key row   | V^T: d row
    const int st_c   = (tid & 3) * 16;    // K: d cols    | V^T: key cols
    const float* kp = K + base + (size_t)st_row * DHEAD + st_c;
    const float* vp = V + base + (size_t)st_c  * DHEAD + st_row;  // transposed gather

    float4 kf[4];
    float  vf[16];
    #pragma unroll
    for (int q = 0; q < 4; ++q) kf[q] = *(const float4*)(kp + 4*q);
    #pragma unroll
    for (int j = 0; j < 16; ++j) vf[j] = vp[(size_t)j * DHEAD];

    f32x4 oacc[4] = {{0.f,0.f,0.f,0.f},{0.f,0.f,0.f,0.f},
                     {0.f,0.f,0.f,0.f},{0.f,0.f,0.f,0.f}};
    float lacc = 0.f;
    _Float16* const sp = &s_p[wave][0];

    // ---------------- pass A: O^T accumulation + row sums ----------------
    for (int jt = 0; jt < NT; ++jt) {
        half8 kh0, kh1, vh0, vh1;
        #pragma unroll
        for (int i = 0; i < 4; ++i) {
            kh0[i]   = (_Float16)kf[0][i]; kh0[i+4] = (_Float16)kf[1][i];
            kh1[i]   = (_Float16)kf[2][i]; kh1[i+4] = (_Float16)kf[3][i];
        }
        #pragma unroll
        for (int i = 0; i < 8; ++i) { vh0[i] = (_Float16)vf[i]; vh1[i] = (_Float16)vf[i+8]; }
        __syncthreads();   // previous tile's LDS reads complete
        *(half8*)&s_k[st_row * LDT + st_c    ] = kh0;
        *(half8*)&s_k[st_row * LDT + st_c + 8] = kh1;
        *(half8*)&s_v[st_row * LDT + st_c    ] = vh0;
        *(half8*)&s_v[st_row * LDT + st_c + 8] = vh1;
        __syncthreads();
        if (jt + 1 < NT) {   // prefetch next tile into regs; latency hides under compute
            kp += 64 * DHEAD; vp += 64 * DHEAD;
            #pragma unroll
            for (int q = 0; q < 4; ++q) kf[q] = *(const float4*)(kp + 4*q);
            #pragma unroll
            for (int j = 0; j < 16; ++j) vf[j] = vp[(size_t)j * DHEAD];
        }
        // S^T = K_tile · Q^T : lane holds S[q=l15][key=16*jj+4*quad+r]
        #pragma unroll
        for (int jj = 0; jj < 4; ++jj) {
            const half8 b0 = *(const half8*)&s_k[(16*jj + l15) * LDT + 8*quad];
            const half8 b1 = *(const half8*)&s_k[(16*jj + l15) * LDT + 32 + 8*quad];
            f32x4 acc = {0.f,0.f,0.f,0.f};
            acc = __builtin_amdgcn_mfma_f32_16x16x32_f16(b0, aq[0], acc, 0, 0, 0);
            acc = __builtin_amdgcn_mfma_f32_16x16x32_f16(b1, aq[1], acc, 0, 0, 0);
            half4 ph;
            #pragma unroll
            for (int r = 0; r < 4; ++r) {
                const float p = __expf(acc[r]);
                lacc += p;
                ph[r] = (_Float16)p;
            }
            *(half4*)&sp[l15 * LDT + 16*jj + 4*quad] = ph;   // P[q=l15][4 consecutive keys]
        }
        // s_p is wave-private: wave-local LDS drain instead of __syncthreads
        __asm__ volatile("s_waitcnt lgkmcnt(0)" ::: "memory");
        __builtin_amdgcn_sched_barrier(0);
        const half8 ap0 = *(const half8*)&sp[l15 * LDT + 8*quad];
        const half8 ap1 = *(const half8*)&sp[l15 * LDT + 32 + 8*quad];
        // O^T += V^T · P^T : lane holds O[q=l15][d=16*dt+4*quad+r]
        #pragma unroll
        for (int dt = 0; dt < 4; ++dt) {
            const half8 bv0 = *(const half8*)&s_v[(16*dt + l15) * LDT + 8*quad];
            const half8 bv1 = *(const half8*)&s_v[(16*dt + l15) * LDT + 32 + 8*quad];
            oacc[dt] = __builtin_amdgcn_mfma_f32_16x16x32_f16(bv0, ap0, oacc[dt], 0, 0, 0);
            oacc[dt] = __builtin_amdgcn_mfma_f32_16x16x32_f16(bv1, ap1, oacc[dt], 0, 0, 0);
        }
    }

    // row sum for q = l15 lives in the 4 quads: 2 shuffles, inv is per-lane
    lacc += __shfl_xor(lacc, 16);
    lacc += __shfl_xor(lacc, 32);
    const float inv = 1.0f / lacc;

    {   // O[q=gr0+l15][16*dt+4*quad .. +3] — vectorized, non-temporal
        float* op = out + base + (size_t)(gr0 + l15) * DHEAD;
        #pragma unroll
        for (int dt = 0; dt < 4; ++dt) {
            f32x4 ov;
            #pragma unroll
            for (int r = 0; r < 4; ++r) ov[r] = oacc[dt][r] * inv;
            __builtin_nontemporal_store(ov, (f32x4*)(op + 16*dt + 4*quad));
        }
    }

    // ---------------- pass B: recompute S^T, stream attention rows ----------------
    kp = K + base + (size_t)st_row * DHEAD + st_c;
    #pragma unroll
    for (int q = 0; q < 4; ++q) kf[q] = *(const float4*)(kp + 4*q);
    float* const arow = out + (size_t)NBH * N_CTX * DHEAD
                      + (size_t)bh * N_CTX * N_CTX + (size_t)(gr0 + l15) * N_CTX;
    for (int jt = 0; jt < NT; ++jt) {
        half8 kh0, kh1;
        #pragma unroll
        for (int i = 0; i < 4; ++i) {
            kh0[i]   = (_Float16)kf[0][i]; kh0[i+4] = (_Float16)kf[1][i];
            kh1[i]   = (_Float16)kf[2][i]; kh1[i+4] = (_Float16)kf[3][i];
        }
        __syncthreads();
        *(half8*)&s_k[st_row * LDT + st_c    ] = kh0;
        *(half8*)&s_k[st_row * LDT + st_c + 8] = kh1;
        __syncthreads();
        if (jt + 1 < NT) {
            kp += 64 * DHEAD;
            #pragma unroll
            for (int q = 0; q < 4; ++q) kf[q] = *(const float4*)(kp + 4*q);
        }
        const int j0 = jt * 64;
        #pragma unroll
        for (int jj = 0; jj < 4; ++jj) {
            const half8 b0 = *(const half8*)&s_k[(16*jj + l15) * LDT + 8*quad];
            const half8 b1 = *(const half8*)&s_k[(16*jj + l15) * LDT + 32 + 8*quad];
            f32x4 acc = {0.f,0.f,0.f,0.f};
            acc = __builtin_amdgcn_mfma_f32_16x16x32_f16(b0, aq[0], acc, 0, 0, 0);
            acc = __builtin_amdgcn_mfma_f32_16x16x32_f16(b1, aq[1], acc, 0, 0, 0);
            f32x4 av;
            #pragma unroll
            for (int r = 0; r < 4; ++r) av[r] = __expf(acc[r]) * inv;
            // lane writes attention[q=gr0+l15][j0+16*jj+4*quad .. +3]; 64 lanes of a
            // wave cover 16 rows x 64B full lines per instr; nt keeps K/V in L2/L3
            __builtin_nontemporal_store(av, (f32x4*)(arow + j0 + 16*jj + 4*quad));
        }
    }
}

extern "C" void kernel_launch(void* const* d_in, const int* in_sizes, int n_in,
                              void* d_out, int out_size, void* d_ws, size_t ws_size,
                              hipStream_t stream)
{
    const float* q = (const float*)d_in[0];
    const float* k = (const float*)d_in[1];
    const float* v = (const float*)d_in[2];
    float* o = (float*)d_out;
    dim3 grid(N_CTX / 64, NBH), block(256);
    hipLaunchKernelGGL(attn_fused, grid, block, 0, stream, q, k, v, o);
}